// Round 1
// baseline (220.683 us; speedup 1.0000x reference)
//
#include <hip/hip_runtime.h>

#define BATCH     32768
#define DFEAT     768
#define NF        64          // fields
#define NE        12          // embedding dim
#define TILE_ROWS 16
#define JG        8           // j-columns per thread
#define NJG       (NF/JG)     // 8 j-groups
#define NTHREADS  (TILE_ROWS*NJG)   // 128
#define ROW_F4    (DFEAT/4)   // 192 float4 per row

// XOR-swizzle float4 slots within each 128B segment so that the 8 distinct
// rows read by a wave in the hot loop land in 8 distinct bank groups
// (row stride 768 words == 0 mod 32 banks would otherwise be 8-way conflict;
// padding is impossible: 16KB S + 48KB X is exactly the 64KB block LDS cap).
__device__ __forceinline__ int xs_word(int r, int c4) {
    return r * DFEAT + (((c4 & ~7) | ((c4 ^ r) & 7)) << 2);
}

__global__ __launch_bounds__(NTHREADS, 1) void ffm_kernel(
    const float* __restrict__ x,
    const float* __restrict__ W,
    const float* __restrict__ bvec,
    const float* __restrict__ V,
    float* __restrict__ out)
{
    __shared__ float S_lds[NF * NF];          // 16 KB
    __shared__ float Xs[TILE_ROWS * DFEAT];   // 48 KB (swizzled)

    const int tid = threadIdx.x;

    // ---- S[i][j] = (i!=j) ? 0.5*<V[i,j,:],V[j,i,:]> : 0   (symmetric form)
    for (int idx = tid; idx < NF * NF; idx += NTHREADS) {
        const int i = idx >> 6, j = idx & 63;
        const float4 a = *(const float4*)(V + (size_t)((i << 6) | j) * 4);
        const float4 b = *(const float4*)(V + (size_t)((j << 6) | i) * 4);
        S_lds[idx] = (i == j) ? 0.0f
                   : 0.5f * (a.x * b.x + a.y * b.y + a.z * b.z + a.w * b.w);
    }

    // ---- stage 16-row X tile (coalesced float4 loads)
    const int row0 = blockIdx.x * TILE_ROWS;
    const float4* xg = (const float4*)(x + (size_t)row0 * DFEAT);
    #pragma unroll
    for (int k = 0; k < TILE_ROWS * ROW_F4 / NTHREADS; ++k) {   // 24 iters
        const int f  = k * NTHREADS + tid;
        const int r  = f / ROW_F4;
        const int c4 = f % ROW_F4;
        *(float4*)(Xs + xs_word(r, c4)) = xg[f];
    }
    __syncthreads();

    const int r  = tid >> 3;   // row within tile, 8 lanes share r (LDS bcast)
    const int jg = tid & 7;    // j-group

    float acc[JG][NE];
    #pragma unroll
    for (int jj = 0; jj < JG; ++jj)
        #pragma unroll
        for (int e = 0; e < NE; ++e) acc[jj][e] = 0.0f;

    // ---- hot loop: acc[j][e] += S[i][j] * x[i][e]  (5 b128 LDS + 96 FMA / i)
    #pragma unroll 2
    for (int i = 0; i < NF; ++i) {
        const float4 s0 = *(const float4*)(S_lds + i * NF + jg * JG);
        const float4 s1 = *(const float4*)(S_lds + i * NF + jg * JG + 4);
        const float4 x0 = *(const float4*)(Xs + xs_word(r, i * 3 + 0));
        const float4 x1 = *(const float4*)(Xs + xs_word(r, i * 3 + 1));
        const float4 x2 = *(const float4*)(Xs + xs_word(r, i * 3 + 2));
        const float ss[JG] = {s0.x, s0.y, s0.z, s0.w, s1.x, s1.y, s1.z, s1.w};
        const float xv[NE] = {x0.x, x0.y, x0.z, x0.w, x1.x, x1.y, x1.z, x1.w,
                              x2.x, x2.y, x2.z, x2.w};
        #pragma unroll
        for (int jj = 0; jj < JG; ++jj)
            #pragma unroll
            for (int e = 0; e < NE; ++e)
                acc[jj][e] = fmaf(ss[jj], xv[e], acc[jj][e]);
    }

    // ---- epilogue: p = sum_j x_j*(t_j + W_j)  (interaction + linear fused)
    float p = 0.0f;
    #pragma unroll
    for (int jj = 0; jj < JG; ++jj) {
        const int j = jg * JG + jj;
        #pragma unroll
        for (int q = 0; q < 3; ++q) {
            const float4 xv = *(const float4*)(Xs + xs_word(r, j * 3 + q));
            const float4 wv = *(const float4*)(W + j * NE + q * 4);
            p += xv.x * (acc[jj][q * 4 + 0] + wv.x);
            p += xv.y * (acc[jj][q * 4 + 1] + wv.y);
            p += xv.z * (acc[jj][q * 4 + 2] + wv.z);
            p += xv.w * (acc[jj][q * 4 + 3] + wv.w);
        }
    }

    // ---- reduce 8 partials per row (lanes r*8 .. r*8+7, same wave)
    p += __shfl_xor(p, 1);
    p += __shfl_xor(p, 2);
    p += __shfl_xor(p, 4);

    if (jg == 0) {
        const float z = p + bvec[0];
        out[row0 + r] = 1.0f / (1.0f + __expf(-z));
    }
}

extern "C" void kernel_launch(void* const* d_in, const int* in_sizes, int n_in,
                              void* d_out, int out_size, void* d_ws, size_t ws_size,
                              hipStream_t stream) {
    const float* x  = (const float*)d_in[0];
    const float* W  = (const float*)d_in[1];  // [1,768]
    const float* bb = (const float*)d_in[2];  // [1]
    const float* V  = (const float*)d_in[3];  // [64,64,4]
    float* out = (float*)d_out;               // [32768]
    ffm_kernel<<<dim3(BATCH / TILE_ROWS), dim3(NTHREADS), 0, stream>>>(
        x, W, bb, V, out);
}

// Round 2
// 172.388 us; speedup vs baseline: 1.2802x; 1.2802x over previous
//
#include <hip/hip_runtime.h>

#define BATCH   32768
#define DFEAT   768
#define NF      64     // fields
#define NE      12     // embedding dim
#define NTHR    256    // 4 waves
#define RPW     5      // rows per wave (12 e-lanes each, lanes 60..63 idle)
#define ROWS_PB (4*RPW)          // 20 rows per block
#define NBLK    ((BATCH + ROWS_PB - 1) / ROWS_PB)   // 1639
#define PF      8      // x prefetch depth

// ---- pre-kernel: S[i][j] = (i!=j) ? 0.5*<V[i,j,:],V[j,i,:]> : 0  -> d_ws
__global__ void s_prep_kernel(const float* __restrict__ V, float* __restrict__ S) {
    const int idx = blockIdx.x * 256 + threadIdx.x;
    if (idx >= NF * NF) return;
    const int i = idx >> 6, j = idx & 63;
    const float4 a = *(const float4*)(V + (size_t)((i << 6) | j) * 4);
    const float4 b = *(const float4*)(V + (size_t)((j << 6) | i) * 4);
    S[idx] = (i == j) ? 0.0f
           : 0.5f * (a.x * b.x + a.y * b.y + a.z * b.z + a.w * b.w);
}

// Hot loop is pure v_fma(sgpr_S, vgpr_x, vgpr_acc): S arrives via the scalar
// cache (wave-uniform address -> s_load), x streams from global with an
// 8-deep register prefetch, acc[64] lives in VGPRs. No LDS in the hot loop.
__global__ __launch_bounds__(NTHR, 4) void ffm_kernel(
    const float* __restrict__ x,
    const float* __restrict__ W,
    const float* __restrict__ bvec,
    const float* __restrict__ S,   // d_ws, [64][64], pre-halved, zero diag
    float* __restrict__ out)
{
    __shared__ float red[NTHR];

    const int tid  = threadIdx.x;
    const int w    = tid >> 6;
    const int lane = tid & 63;
    const int r    = lane / NE;          // 0..5 (5 => idle lane)
    const int e    = lane - r * NE;      // 0..11

    int row = blockIdx.x * ROWS_PB + w * RPW + (r < RPW ? r : 0);
    if (row >= BATCH) row = BATCH - 1;   // clamped lanes compute garbage, never store

    const float* xrow = x + (size_t)row * DFEAT + e;   // x[row][i][e] at xrow[i*12]

    float acc[NF];
    #pragma unroll
    for (int j = 0; j < NF; ++j) acc[j] = 0.0f;

    float xbuf[PF];
    #pragma unroll
    for (int u = 0; u < PF; ++u) xbuf[u] = xrow[u * NE];

    for (int i8 = 0; i8 < NF; i8 += PF) {
        #pragma unroll
        for (int u = 0; u < PF; ++u) {
            const int i = i8 + u;
            const float xv = xbuf[u];
            const float* srow = S + i * NF;   // wave-uniform -> s_load
            #pragma unroll
            for (int j = 0; j < NF; ++j)
                acc[j] = fmaf(srow[j], xv, acc[j]);
            const int inext = (i + PF < NF) ? (i + PF) : (NF - 1);
            xbuf[u] = xrow[inext * NE];
        }
    }

    // epilogue: p = sum_j x[row][j][e] * (acc[j] + W[j*12+e])
    // x reload hits L1/L2 (this wave streamed it moments ago); W is 3 KB, hot.
    float p = 0.0f;
    #pragma unroll
    for (int j = 0; j < NF; ++j) {
        const float xj = xrow[j * NE];
        const float wj = W[j * NE + e];
        p = fmaf(xj, acc[j] + wj, p);
    }

    red[tid] = p;
    __syncthreads();

    if (tid < ROWS_PB) {
        const int w2 = tid / RPW, r2 = tid - w2 * RPW;
        const int orow = blockIdx.x * ROWS_PB + w2 * RPW + r2;
        if (orow < BATCH) {
            float s = 0.0f;
            #pragma unroll
            for (int q = 0; q < NE; ++q) s += red[(w2 << 6) + r2 * NE + q];
            const float z = s + bvec[0];
            out[orow] = 1.0f / (1.0f + __expf(-z));
        }
    }
}

extern "C" void kernel_launch(void* const* d_in, const int* in_sizes, int n_in,
                              void* d_out, int out_size, void* d_ws, size_t ws_size,
                              hipStream_t stream) {
    const float* x  = (const float*)d_in[0];
    const float* W  = (const float*)d_in[1];  // [1,768]
    const float* bb = (const float*)d_in[2];  // [1]
    const float* V  = (const float*)d_in[3];  // [64,64,4]
    float* S   = (float*)d_ws;                // 16 KB scratch
    float* out = (float*)d_out;               // [32768]

    s_prep_kernel<<<dim3((NF * NF + 255) / 256), dim3(256), 0, stream>>>(V, S);
    ffm_kernel<<<dim3(NBLK), dim3(NTHR), 0, stream>>>(x, W, bb, S, out);
}